// Round 8
// baseline (150.586 us; speedup 1.0000x reference)
//
#include <hip/hip_runtime.h>
#include <hip/hip_bf16.h>

#define DEV __device__ __forceinline__
#define AS1 __attribute__((address_space(1)))
#define AS3 __attribute__((address_space(3)))

typedef __attribute__((ext_vector_type(8))) short bf16x8;
typedef __attribute__((ext_vector_type(4))) float f32x4;

static constexpr int NR   = 16384;
static constexpr int DIN  = 512;
static constexpr int DHID = 2048;
static constexpr int DOUT = 512;
static constexpr int LR   = 64;          // 4 bands * rank 16
static constexpr int K1   = DIN + LR;    // 576
static constexpr int K2   = DHID + LR;   // 2112

DEV unsigned short f2bf(float f) {
  unsigned u = __float_as_uint(f);
  u += 0x7fffu + ((u >> 16) & 1u);
  return (unsigned short)(u >> 16);
}

// fast GELU: tanh-form, |err vs erf-form| < ~1.5e-3 (well under bf16 quantum of h)
DEV float fast_gelu(float v) {
  float x2 = v * v;
  float a  = -v * __builtin_fmaf(0.10294324f, x2, 2.30220817f);
  float t  = exp2f(a);
  return v * __builtin_amdgcn_rcpf(1.0f + t);
}

template<int N> DEV void wvm() {
  asm volatile("s_waitcnt vmcnt(%0)" :: "i"(N) : "memory");
}

// ---- x fp32 -> bf16 into xaug[:, 0:512] (row stride K1) ----
__global__ __launch_bounds__(256) void cvt_x_kernel(const float* __restrict__ x,
                                                    unsigned short* __restrict__ xaug) {
  int i = blockIdx.x * 256 + threadIdx.x;   // one float4 per thread
  if (i >= NR * DIN / 4) return;
  int e = i * 4;
  int r = e >> 9, c = e & 511;
  float4 v = ((const float4*)x)[i];
  uint2 o;
  o.x = (unsigned)f2bf(v.x) | ((unsigned)f2bf(v.y) << 16);
  o.y = (unsigned)f2bf(v.z) | ((unsigned)f2bf(v.w) << 16);
  *(uint2*)(xaug + (size_t)r * K1 + c) = o;
}

// ---- generic transpose+convert: in fp32 [R][C] -> out bf16 [C][LDO] at col offset CO ----
template<int R, int C, int LDO, int CO>
__global__ __launch_bounds__(256) void tconv_kernel(const float* __restrict__ in,
                                                    unsigned short* __restrict__ out) {
  __shared__ float t[32][33];
  int bc = blockIdx.x * 32, br = blockIdx.y * 32;
  int tx = threadIdx.x & 31, ty = threadIdx.x >> 5;   // ty 0..7
  #pragma unroll
  for (int i = 0; i < 32; i += 8)
    t[ty + i][tx] = in[(size_t)(br + ty + i) * C + bc + tx];
  __syncthreads();
  #pragma unroll
  for (int i = 0; i < 32; i += 8)
    out[(size_t)(bc + ty + i) * LDO + CO + br + tx] = f2bf(t[tx][ty + i]);
}

// ---- LoRA A rearrange: A [4][D][16] fp32 -> AT [64][D] bf16 ----
__global__ __launch_bounds__(256) void rearrA_kernel(const float* __restrict__ A,
                                                     unsigned short* __restrict__ AT, int D) {
  int tid = blockIdx.x * 256 + threadIdx.x;
  if (tid >= 64 * D) return;
  int j = tid / D, i = tid - j * D;
  AT[tid] = f2bf(A[((size_t)(j >> 4) * D + i) * 16 + (j & 15)]);
}

// ============ m201-style 8-phase 2-tile-per-iter MFMA GEMM (T2+T3+T4+T5) ============
// BM=256 fixed. 8 waves as MWxNW. Wave tile (BM/MW)x(BN/NW); quadrant = half of each.
// LDS: [2buf][2half] for A (128x64 halves) and B (BN/2 x 64 halves).
// Iter j: compute T0=2j (even buf) ph1-4, T1=2j+1 (odd) ph5-8; quadrant order
// (0,0),(0,1),(1,1),(1,0). bfv both-halves resident; af reloaded at ph1/ph3.
// Stage ledger: ph1:A0(T1) ph2:A1(T1) ph3:B0(T2) ph4:B1(T2) ph5:A0(T2) ph6:A1(T2)
// ph7:B0(T3) ph8:B1(T3). Slot-free proof: B-halves last read ph2/ph6, A-halves
// ph3/ph7; each stage issues >=1 barrier after its slot's last reader.
// Waits: ONLY end-ph4 & end-ph8 vmcnt(2*BL) (FIFO: lands exactly the halves the
// next 4 phases read; >=3-phase latency cover). Tails drain exactly; odd NT gets
// a leftover-tile block (staged as T2 by the last iteration).
// EPI: 0 = gelu(acc+bias)->bf16 out ; 1 = acc+bias->fp32 out
template<int BM, int BN, int MW, int K, int EPI>
__global__ __launch_bounds__(512, 2) void gemm8_kernel(
    const unsigned short* __restrict__ A, int lda,
    const unsigned short* __restrict__ B, int ldb,
    const float* __restrict__ bias,
    void* __restrict__ outp, int ldo, int ocol) {
  constexpr int NW  = 8 / MW;
  constexpr int WMR = BM / MW, WNC = BN / NW;
  constexpr int QR  = WMR / 2, QC = WNC / 2;
  constexpr int MQ  = QR / 16, NQ = QC / 16;
  constexpr int AL  = 2;                 // loads/thread per A half (128x64 bf16)
  constexpr int BL  = BN / 128;          // loads/thread per B half
  constexpr int HA  = 128 * 64;
  constexpr int HB  = (BN / 2) * 64;
  constexpr int NT  = K / 64;
  constexpr int NJ  = NT / 2;
  static_assert(BM == 256 && NT >= 3, "geometry");
  __shared__ __align__(16) unsigned short lA[2 * 2 * HA];   // [buf][half]
  __shared__ __align__(16) unsigned short lB[2 * 2 * HB];

  const int tid  = threadIdx.x;
  const int w    = tid >> 6, lane = tid & 63;
  const int wr   = w / NW, wc = w % NW;
  const int ah   = wr / (MW / 2);                    // wave's A half
  const int rloc = (wr % (MW / 2)) * WMR;            // row offset within half
  const int bh   = wc / (NW / 2);                    // wave's B half
  const int cloc = (wc % (NW / 2)) * WNC;
  const int bm   = blockIdx.x * BM, bn = blockIdx.y * BN;
  const int l15  = lane & 15;
  const int kc0  = ((lane >> 4) ^ (lane & 7)) * 8;        // kk=0 chunk (swizzled)
  const int kc1  = (((lane >> 4) + 4) ^ (lane & 7)) * 8;  // kk=1 chunk

  f32x4 acc[2][2][MQ][NQ] = {};   // [qm][qn][m][n]
  bf16x8 af[MQ][2];               // current qm's A frags
  bf16x8 bfv[2][NQ][2];           // [qn][n][kk], both halves resident

  auto stageA = [&](int buf, int half, int t) {
    #pragma unroll
    for (int i = 0; i < AL; ++i) {
      int row = (w * AL + i) * 8 + (lane >> 3);
      __builtin_amdgcn_global_load_lds(
          (const AS1 void*)(A + (size_t)(bm + half * 128 + row) * lda
                              + (size_t)t * 64 + (((lane & 7) ^ (row & 7)) * 8)),
          (AS3 void*)(lA + (buf * 2 + half) * HA + (w * AL + i) * 512),
          16, 0, 0);
    }
  };
  auto stageB = [&](int buf, int half, int t) {
    #pragma unroll
    for (int i = 0; i < BL; ++i) {
      int row = (w * BL + i) * 8 + (lane >> 3);
      __builtin_amdgcn_global_load_lds(
          (const AS1 void*)(B + (size_t)(bn + half * (BN / 2) + row) * ldb
                              + (size_t)t * 64 + (((lane & 7) ^ (row & 7)) * 8)),
          (AS3 void*)(lB + (buf * 2 + half) * HB + (w * BL + i) * 512),
          16, 0, 0);
    }
  };
  auto ldA = [&](int buf, int qm) {
    const unsigned short* sA = lA + (buf * 2 + ah) * HA;
    #pragma unroll
    for (int m = 0; m < MQ; ++m) {
      int ro = (rloc + qm * QR + m * 16 + l15) * 64;
      af[m][0] = *(const bf16x8*)(sA + ro + kc0);
      af[m][1] = *(const bf16x8*)(sA + ro + kc1);
    }
  };
  auto ldB = [&](int buf, int qn) {
    const unsigned short* sB = lB + (buf * 2 + bh) * HB;
    #pragma unroll
    for (int n = 0; n < NQ; ++n) {
      int ro = (cloc + qn * QC + n * 16 + l15) * 64;
      bfv[qn][n][0] = *(const bf16x8*)(sB + ro + kc0);
      bfv[qn][n][1] = *(const bf16x8*)(sB + ro + kc1);
    }
  };

#define MFMA_Q(qm, qn)                                                           \
  __builtin_amdgcn_s_setprio(1);                                                 \
  _Pragma("unroll")                                                              \
  for (int m = 0; m < MQ; ++m)                                                   \
    _Pragma("unroll")                                                            \
    for (int n = 0; n < NQ; ++n) {                                               \
      acc[qm][qn][m][n] = __builtin_amdgcn_mfma_f32_16x16x32_bf16(               \
          af[m][0], bfv[qn][n][0], acc[qm][qn][m][n], 0, 0, 0);                  \
      acc[qm][qn][m][n] = __builtin_amdgcn_mfma_f32_16x16x32_bf16(               \
          af[m][1], bfv[qn][n][1], acc[qm][qn][m][n], 0, 0, 0);                  \
    }                                                                            \
  __builtin_amdgcn_s_setprio(0);

#define BAR() __builtin_amdgcn_s_barrier()

  // prologue FIFO: B0(t0),B1(t0),A0(t0),A1(t0),B0(t1),B1(t1); land t0, keep B(t1) in flight
  stageB(0, 0, 0); stageB(0, 1, 0); stageA(0, 0, 0); stageA(0, 1, 0);
  stageB(1, 0, 1); stageB(1, 1, 1);
  wvm<2 * BL>();
  BAR();

  for (int j = 0; j < NJ; ++j) {
    const int T1 = 2 * j + 1, T2 = 2 * j + 2, T3 = 2 * j + 3;
    // ---- ph1: T0 q(0,0)
    ldA(0, 0); ldB(0, 0);
    stageA(1, 0, T1);
    BAR();
    MFMA_Q(0, 0);
    BAR();
    // ---- ph2: T0 q(0,1)
    ldB(0, 1);
    stageA(1, 1, T1);
    BAR();
    MFMA_Q(0, 1);
    BAR();
    // ---- ph3: T0 q(1,1)
    ldA(0, 1);
    if (T2 < NT) stageB(0, 0, T2);
    BAR();
    MFMA_Q(1, 1);
    BAR();
    // ---- ph4: T0 q(1,0)  (no ds reads)
    if (T2 < NT) stageB(0, 1, T2);
    BAR();
    MFMA_Q(1, 0);
    if (T2 < NT) wvm<2 * BL>(); else wvm<0>();   // land B(T1)+A(T1)
    BAR();
    // ---- ph5: T1 q(0,0)
    ldA(1, 0); ldB(1, 0);
    if (T2 < NT) stageA(0, 0, T2);
    BAR();
    MFMA_Q(0, 0);
    BAR();
    // ---- ph6: T1 q(0,1)
    ldB(1, 1);
    if (T2 < NT) stageA(0, 1, T2);
    BAR();
    MFMA_Q(0, 1);
    BAR();
    // ---- ph7: T1 q(1,1)
    ldA(1, 1);
    if (T3 < NT) stageB(1, 0, T3);
    BAR();
    MFMA_Q(1, 1);
    BAR();
    // ---- ph8: T1 q(1,0)
    if (T3 < NT) stageB(1, 1, T3);
    BAR();
    MFMA_Q(1, 0);
    if (T3 < NT) wvm<2 * BL>(); else wvm<0>();   // land B(T2)+A(T2)
    BAR();
  }

  // leftover tile (NT odd): staged into even buf as T2 by the last iteration
  if (NT & 1) {
    ldA(0, 0); ldB(0, 0);
    MFMA_Q(0, 0);
    ldB(0, 1);
    MFMA_Q(0, 1);
    ldA(0, 1);
    MFMA_Q(1, 1);
    MFMA_Q(1, 0);
  }
#undef MFMA_Q
#undef BAR

  // epilogue: C/D layout col=lane&15, row=(lane>>4)*4+reg
  float biasv[2][NQ];
  #pragma unroll
  for (int qn = 0; qn < 2; ++qn)
    #pragma unroll
    for (int n = 0; n < NQ; ++n)
      biasv[qn][n] = bias[bn + bh * (BN / 2) + cloc + qn * QC + n * 16 + l15];

  #pragma unroll
  for (int qm = 0; qm < 2; ++qm)
    #pragma unroll
    for (int qn = 0; qn < 2; ++qn)
      #pragma unroll
      for (int m = 0; m < MQ; ++m)
        #pragma unroll
        for (int n = 0; n < NQ; ++n) {
          int col  = bn + bh * (BN / 2) + cloc + qn * QC + n * 16 + l15;
          int rowb = bm + ah * 128 + rloc + qm * QR + m * 16 + ((lane >> 4) << 2);
          #pragma unroll
          for (int r = 0; r < 4; ++r) {
            float v = acc[qm][qn][m][n][r];
            int row = rowb + r;
            if (EPI == 0) {
              v = fast_gelu(v + biasv[qn][n]);
              ((unsigned short*)outp)[(size_t)row * ldo + ocol + col] = f2bf(v);
            } else {
              v += biasv[qn][n];
              ((float*)outp)[(size_t)row * ldo + col] = v;
            }
          }
        }
}

// ==================== small 2-phase GEMM for the LoRA u-projections ====================
// (validated R4 structure: BK=32 triple-buffer ring, counted vmcnt)
// EPI2: acc*2*bw[row][col>>4] -> bf16 out at col offset
template<int BM, int BN, int WM, int WN, int K>
__global__ __launch_bounds__(256) void gemmu_kernel(
    const unsigned short* __restrict__ A, int lda,
    const unsigned short* __restrict__ B, int ldb,
    const float* __restrict__ bw,
    unsigned short* __restrict__ outp, int ldo, int ocol) {
  constexpr int WRM = WM / 16, WRN = WN / 16;
  constexpr int NWN = BN / WN;
  constexpr int NT  = K / 32;
  constexpr int NBUF = 3;
  constexpr int AISS = BM / 64;
  constexpr int BISS = BN / 64;
  constexpr int LOADS = AISS + BISS;
  static_assert((BM / WM) * (BN / WN) == 4, "4 waves");
  __shared__ __align__(16) unsigned short lA[NBUF * BM * 32];
  __shared__ __align__(16) unsigned short lB[NBUF * BN * 32];

  const int tid  = threadIdx.x;
  const int wid  = tid >> 6, lane = tid & 63;
  const int wr   = wid / NWN, wc = wid % NWN;
  const int bm   = blockIdx.x * BM, bn = blockIdx.y * BN;
  const int srow = lane >> 2;
  const int scol = (((lane & 3) ^ ((lane >> 2) & 3)) * 8);
  const int kch  = (((lane >> 4) ^ (lane & 3)) * 8);

  f32x4 acc[WRM][WRN] = {};

  auto stage = [&](int buf, int t) {
    #pragma unroll
    for (int i = 0; i < AISS; i++) {
      int row = i * 64 + wid * 16 + srow;
      __builtin_amdgcn_global_load_lds(
          (const AS1 void*)(A + (size_t)(bm + row) * lda + t * 32 + scol),
          (AS3 void*)(lA + buf * (BM * 32) + i * 2048 + wid * 512), 16, 0, 0);
    }
    #pragma unroll
    for (int i = 0; i < BISS; i++) {
      int row = i * 64 + wid * 16 + srow;
      __builtin_amdgcn_global_load_lds(
          (const AS1 void*)(B + (size_t)(bn + row) * ldb + t * 32 + scol),
          (AS3 void*)(lB + buf * (BN * 32) + i * 2048 + wid * 512), 16, 0, 0);
    }
  };
  auto compute = [&](int buf) {
    const unsigned short* pA = lA + buf * (BM * 32);
    const unsigned short* pB = lB + buf * (BN * 32);
    bf16x8 af[WRM], bfv[WRN];
    #pragma unroll
    for (int m = 0; m < WRM; m++)
      af[m] = *(const bf16x8*)(pA + (wr * WM + m * 16 + (lane & 15)) * 32 + kch);
    #pragma unroll
    for (int n = 0; n < WRN; n++)
      bfv[n] = *(const bf16x8*)(pB + (wc * WN + n * 16 + (lane & 15)) * 32 + kch);
    #pragma unroll
    for (int m = 0; m < WRM; m++)
      #pragma unroll
      for (int n = 0; n < WRN; n++)
        acc[m][n] = __builtin_amdgcn_mfma_f32_16x16x32_bf16(af[m], bfv[n], acc[m][n], 0, 0, 0);
  };

  stage(0, 0); stage(1, 1); stage(2, 2);
  wvm<2 * LOADS>();
  __builtin_amdgcn_s_barrier();

  int bt = 0;
  for (int t = 0; t < NT; ++t) {
    compute(bt);
    __builtin_amdgcn_s_barrier();
    if (t + 1 < NT) {
      if (t + NBUF < NT) stage(bt, t + NBUF);
      int newer = (t + NBUF < NT) ? (NBUF - 1) : (NT - 2 - t);
      if (newer >= 2)      wvm<2 * LOADS>();
      else if (newer == 1) wvm<LOADS>();
      else                 wvm<0>();
      __builtin_amdgcn_s_barrier();
      bt = (bt == NBUF - 1) ? 0 : bt + 1;
    }
  }

  const int r0 = bm + wr * WM;
  const int c0 = bn + wc * WN;
  #pragma unroll
  for (int m = 0; m < WRM; m++)
    #pragma unroll
    for (int n = 0; n < WRN; n++) {
      int col  = c0 + n * 16 + (lane & 15);
      int rowb = r0 + m * 16 + ((lane >> 4) << 2);
      #pragma unroll
      for (int r = 0; r < 4; r++) {
        float v = acc[m][n][r] * 2.0f * bw[(rowb + r) * 4 + (col >> 4)];
        outp[(size_t)(rowb + r) * ldo + ocol + col] = f2bf(v);
      }
    }
}

extern "C" void kernel_launch(void* const* d_in, const int* in_sizes, int n_in,
                              void* d_out, int out_size, void* d_ws, size_t ws_size,
                              hipStream_t stream) {
  const float* x  = (const float*)d_in[0];
  const float* bw = (const float*)d_in[1];
  const float* W1 = (const float*)d_in[2];
  const float* b1 = (const float*)d_in[3];
  const float* W2 = (const float*)d_in[4];
  const float* b2 = (const float*)d_in[5];
  const float* A1 = (const float*)d_in[6];
  const float* B1 = (const float*)d_in[7];
  const float* A2 = (const float*)d_in[8];
  const float* B2 = (const float*)d_in[9];
  float* out = (float*)d_out;

  char* w = (char*)d_ws;
  unsigned short* xaug = (unsigned short*)w;  w += (size_t)NR * K1 * 2;       // 18.9 MB
  unsigned short* haug = (unsigned short*)w;  w += (size_t)NR * K2 * 2;       // 69.2 MB
  unsigned short* W1cT = (unsigned short*)w;  w += (size_t)DHID * K1 * 2;     // 2.36 MB
  unsigned short* W2cT = (unsigned short*)w;  w += (size_t)DOUT * K2 * 2;     // 2.16 MB
  unsigned short* A1T  = (unsigned short*)w;  w += (size_t)64 * DIN * 2;
  unsigned short* A2T  = (unsigned short*)w;  w += (size_t)64 * DHID * 2;

  // --- preprocessing ---
  cvt_x_kernel<<<NR * DIN / 4 / 256, 256, 0, stream>>>(x, xaug);
  tconv_kernel<512, 2048, K1, 0><<<dim3(64, 16), 256, 0, stream>>>(W1, W1cT);
  tconv_kernel<64, 2048, K1, 512><<<dim3(64, 2), 256, 0, stream>>>(B1, W1cT);
  tconv_kernel<2048, 512, K2, 0><<<dim3(16, 64), 256, 0, stream>>>(W2, W2cT);
  tconv_kernel<64, 512, K2, 2048><<<dim3(16, 2), 256, 0, stream>>>(B2, W2cT);
  rearrA_kernel<<<128, 256, 0, stream>>>(A1, A1T, 512);
  rearrA_kernel<<<512, 256, 0, stream>>>(A2, A2T, 2048);

  // --- u1 = 2*bw ⊙ (x @ A1cat)  -> xaug[:, 512:576] ---
  gemmu_kernel<64, 64, 32, 32, 512><<<dim3(NR / 64, 1), 256, 0, stream>>>(
      xaug, K1, A1T, DIN, bw, xaug, K1, 512);
  // --- h = gelu(xaug @ [W1;B1cat] + b1) -> haug[:, 0:2048]  (256x256, 2Mx4N) ---
  gemm8_kernel<256, 256, 2, K1, 0><<<dim3(NR / 256, DHID / 256), 512, 0, stream>>>(
      xaug, K1, W1cT, K1, b1, haug, K2, 0);
  // --- u2 = 2*bw ⊙ (h @ A2cat) -> haug[:, 2048:2112] ---
  gemmu_kernel<64, 64, 32, 32, 2048><<<dim3(NR / 64, 1), 256, 0, stream>>>(
      haug, K2, A2T, DHID, bw, haug, K2, 2048);
  // --- out = haug @ [W2;B2cat] + b2 (fp32)  (256x128, 4Mx2N, 1 block/CU) ---
  gemm8_kernel<256, 128, 4, K2, 1><<<dim3(NR / 256, DOUT / 128), 512, 0, stream>>>(
      haug, K2, W2cT, K2, b2, out, DOUT, 0);
}

// Round 9
// 144.997 us; speedup vs baseline: 1.0385x; 1.0385x over previous
//
#include <hip/hip_runtime.h>
#include <hip/hip_bf16.h>

#define DEV __device__ __forceinline__
#define AS1 __attribute__((address_space(1)))
#define AS3 __attribute__((address_space(3)))

typedef __attribute__((ext_vector_type(8))) short bf16x8;
typedef __attribute__((ext_vector_type(4))) float f32x4;

static constexpr int NR   = 16384;
static constexpr int DIN  = 512;
static constexpr int DHID = 2048;
static constexpr int DOUT = 512;
static constexpr int LR   = 64;          // 4 bands * rank 16
static constexpr int K1   = DIN + LR;    // 576
static constexpr int K2   = DHID + LR;   // 2112

DEV unsigned short f2bf(float f) {
  unsigned u = __float_as_uint(f);
  u += 0x7fffu + ((u >> 16) & 1u);
  return (unsigned short)(u >> 16);
}

// fast GELU: tanh-form, |err vs erf-form| < ~1.5e-3 (well under bf16 quantum of h)
DEV float fast_gelu(float v) {
  float x2 = v * v;
  float a  = -v * __builtin_fmaf(0.10294324f, x2, 2.30220817f);
  float t  = exp2f(a);
  return v * __builtin_amdgcn_rcpf(1.0f + t);
}

template<int N> DEV void wvm() {
  asm volatile("s_waitcnt vmcnt(%0)" :: "i"(N) : "memory");
}

// ---- x fp32 -> bf16 into xaug[:, 0:512] (row stride K1) ----
__global__ __launch_bounds__(256) void cvt_x_kernel(const float* __restrict__ x,
                                                    unsigned short* __restrict__ xaug) {
  int i = blockIdx.x * 256 + threadIdx.x;   // one float4 per thread
  if (i >= NR * DIN / 4) return;
  int e = i * 4;
  int r = e >> 9, c = e & 511;
  float4 v = ((const float4*)x)[i];
  uint2 o;
  o.x = (unsigned)f2bf(v.x) | ((unsigned)f2bf(v.y) << 16);
  o.y = (unsigned)f2bf(v.z) | ((unsigned)f2bf(v.w) << 16);
  *(uint2*)(xaug + (size_t)r * K1 + c) = o;
}

// ---- generic transpose+convert: in fp32 [R][C] -> out bf16 [C][LDO] at col offset CO ----
template<int R, int C, int LDO, int CO>
__global__ __launch_bounds__(256) void tconv_kernel(const float* __restrict__ in,
                                                    unsigned short* __restrict__ out) {
  __shared__ float t[32][33];
  int bc = blockIdx.x * 32, br = blockIdx.y * 32;
  int tx = threadIdx.x & 31, ty = threadIdx.x >> 5;   // ty 0..7
  #pragma unroll
  for (int i = 0; i < 32; i += 8)
    t[ty + i][tx] = in[(size_t)(br + ty + i) * C + bc + tx];
  __syncthreads();
  #pragma unroll
  for (int i = 0; i < 32; i += 8)
    out[(size_t)(bc + ty + i) * LDO + CO + br + tx] = f2bf(t[tx][ty + i]);
}

// ---- LoRA A rearrange: A [4][D][16] fp32 -> AT [64][D] bf16 ----
__global__ __launch_bounds__(256) void rearrA_kernel(const float* __restrict__ A,
                                                     unsigned short* __restrict__ AT, int D) {
  int tid = blockIdx.x * 256 + threadIdx.x;
  if (tid >= 64 * D) return;
  int j = tid / D, i = tid - j * D;
  AT[tid] = f2bf(A[((size_t)(j >> 4) * D + i) * 16 + (j & 15)]);
}

// ========== 2-barrier/tile double-buffered MFMA GEMM, full-cover counted vmcnt ==========
// Per tile t (buf=t&1, nb=buf^1):
//   ldA(both halves)+ldB0 | stage A0,A1,B0(t+1) | MFMA (0,0),(1,0)
//   wvm(6) [lands B1(t), issued mid-tile t-1]  | BARRIER
//   stage B1(t+1) | ldB1 | MFMA (0,1),(1,1)
//   wvm(2) [lands A0,A1,B0(t+1), issued top of this tile] | BARRIER
// Per-wave FIFO: entry outstanding = [B1(t)x2]; +6 -> wvm6; +2 -> wvm2 -> [B1(t+1)x2].
// Every counted wait is followed by a barrier (cross-wave LDS visibility), and every
// staged half has ~0.8-0.9 tile of latency cover. Prologue: stage tile0, wvm(2), BAR
// (B1(t0) lands at tile0's mid wait). Tails: exact drains.
// EPI: 0 = gelu(acc+bias)->bf16 out ; 1 = acc+bias->fp32 out
template<int BM, int BN, int WAVES, int K, int EPI>
__global__ __launch_bounds__(WAVES * 64, 2) void gemmx_kernel(
    const unsigned short* __restrict__ A, int lda,
    const unsigned short* __restrict__ B, int ldb,
    const float* __restrict__ bias,
    void* __restrict__ outp, int ldo, int ocol) {
  constexpr int THREADS = WAVES * 64;
  constexpr int NT = K / 64;
  constexpr int AL = BM * 4 / THREADS;   // gload_lds/thread per A half (=2)
  constexpr int BL = BN * 4 / THREADS;   // per B half (=2)
  constexpr int HA = (BM / 2) * 64;      // elems per half-slot
  constexpr int HB = (BN / 2) * 64;
  constexpr int MQ = BM / 64;            // m-frags per quadrant per wave
  constexpr int WC = WAVES / 2;
  static_assert(NT >= 2 && AL == 2 && BL == 2, "geometry");
  __shared__ __align__(16) unsigned short lA[4 * HA];   // [buf][half]
  __shared__ __align__(16) unsigned short lB[4 * HB];

  const int tid  = threadIdx.x;
  const int w    = tid >> 6, lane = tid & 63;
  const int wr   = w / WC, wc = w % WC;
  const int bm   = blockIdx.x * BM, bn = blockIdx.y * BN;
  const int l15  = lane & 15;
  const int kc0  = ((lane >> 4) ^ (lane & 7)) * 8;        // kk=0 chunk (swizzled)
  const int kc1  = (((lane >> 4) + 4) ^ (lane & 7)) * 8;  // kk=1 chunk

  f32x4 acc[2][2][MQ][2] = {};   // [mh][nh][m][n]
  bf16x8 af[2][MQ][2];           // [mh][m][kk] -- BOTH A halves resident
  bf16x8 bfv[2][2];              // [n][kk] -- current nh only

  auto stageA = [&](int buf, int half, int t) {
    #pragma unroll
    for (int i = 0; i < AL; ++i) {
      int row = w * (AL * 8) + i * 8 + (lane >> 3);
      __builtin_amdgcn_global_load_lds(
          (const AS1 void*)(A + (size_t)(bm + half * (BM / 2) + row) * lda
                              + (size_t)t * 64 + (((lane & 7) ^ (row & 7)) * 8)),
          (AS3 void*)(lA + (buf * 2 + half) * HA + (w * AL + i) * 512),
          16, 0, 0);
    }
  };
  auto stageB = [&](int buf, int half, int t) {
    #pragma unroll
    for (int i = 0; i < BL; ++i) {
      int row = w * (BL * 8) + i * 8 + (lane >> 3);
      __builtin_amdgcn_global_load_lds(
          (const AS1 void*)(B + (size_t)(bn + half * (BN / 2) + row) * ldb
                              + (size_t)t * 64 + (((lane & 7) ^ (row & 7)) * 8)),
          (AS3 void*)(lB + (buf * 2 + half) * HB + (w * BL + i) * 512),
          16, 0, 0);
    }
  };
  auto ldAall = [&](int buf) {
    #pragma unroll
    for (int mh = 0; mh < 2; ++mh) {
      const unsigned short* sA = lA + (buf * 2 + mh) * HA;
      #pragma unroll
      for (int m = 0; m < MQ; ++m) {
        int ro = (wr * (BM / 4) + m * 16 + l15) * 64;
        af[mh][m][0] = *(const bf16x8*)(sA + ro + kc0);
        af[mh][m][1] = *(const bf16x8*)(sA + ro + kc1);
      }
    }
  };
  auto ldB = [&](int buf, int nh) {
    const unsigned short* sB = lB + (buf * 2 + nh) * HB;
    #pragma unroll
    for (int n = 0; n < 2; ++n) {
      int ro = (wc * 32 + n * 16 + l15) * 64;
      bfv[n][0] = *(const bf16x8*)(sB + ro + kc0);
      bfv[n][1] = *(const bf16x8*)(sB + ro + kc1);
    }
  };

#define MFMA_Q(mh, nh)                                                           \
  __builtin_amdgcn_s_setprio(1);                                                 \
  _Pragma("unroll")                                                              \
  for (int m = 0; m < MQ; ++m)                                                   \
    _Pragma("unroll")                                                            \
    for (int n = 0; n < 2; ++n) {                                                \
      acc[mh][nh][m][n] = __builtin_amdgcn_mfma_f32_16x16x32_bf16(               \
          af[mh][m][0], bfv[n][0], acc[mh][nh][m][n], 0, 0, 0);                  \
      acc[mh][nh][m][n] = __builtin_amdgcn_mfma_f32_16x16x32_bf16(               \
          af[mh][m][1], bfv[n][1], acc[mh][nh][m][n], 0, 0, 0);                  \
    }                                                                            \
  __builtin_amdgcn_s_setprio(0);

#define BAR() __builtin_amdgcn_s_barrier()

  // prologue: stage tile0 (order A0,A1,B0,B1); land A0,A1,B0, keep B1 in flight
  stageA(0, 0, 0); stageA(0, 1, 0); stageB(0, 0, 0); stageB(0, 1, 0);
  wvm<2>();
  BAR();

  for (int t = 0; t < NT; ++t) {
    const int buf = t & 1, nb = buf ^ 1;
    const bool more = (t + 1 < NT);
    ldAall(buf);                    // both A halves -> af
    ldB(buf, 0);                    // bfv <- B half0
    if (more) { stageA(nb, 0, t + 1); stageA(nb, 1, t + 1); stageB(nb, 0, t + 1); }
    MFMA_Q(0, 0);
    MFMA_Q(1, 0);
    if (more) wvm<6>(); else wvm<0>();   // B1(t) landed (issued mid-tile t-1)
    BAR();                               // B1(t) visible to all waves
    if (more) stageB(nb, 1, t + 1);
    ldB(buf, 1);                    // bfv <- B half1
    MFMA_Q(0, 1);
    MFMA_Q(1, 1);
    if (more) {
      wvm<2>();                     // A0,A1,B0(t+1) landed (issued top of tile)
      BAR();
    }
  }
#undef MFMA_Q
#undef BAR

  // epilogue: C/D layout col=lane&15, row=(lane>>4)*4+reg
  float biasv[2][2];
  #pragma unroll
  for (int nh = 0; nh < 2; ++nh)
    #pragma unroll
    for (int n = 0; n < 2; ++n)
      biasv[nh][n] = bias[bn + nh * (BN / 2) + wc * 32 + n * 16 + l15];

  #pragma unroll
  for (int mh = 0; mh < 2; ++mh)
    #pragma unroll
    for (int nh = 0; nh < 2; ++nh)
      #pragma unroll
      for (int m = 0; m < MQ; ++m)
        #pragma unroll
        for (int n = 0; n < 2; ++n) {
          int col  = bn + nh * (BN / 2) + wc * 32 + n * 16 + l15;
          int rowb = bm + mh * (BM / 2) + wr * (BM / 4) + m * 16 + ((lane >> 4) << 2);
          #pragma unroll
          for (int r = 0; r < 4; ++r) {
            float v = acc[mh][nh][m][n][r];
            int row = rowb + r;
            if (EPI == 0) {
              v = fast_gelu(v + biasv[nh][n]);
              ((unsigned short*)outp)[(size_t)row * ldo + ocol + col] = f2bf(v);
            } else {
              v += biasv[nh][n];
              ((float*)outp)[(size_t)row * ldo + col] = v;
            }
          }
        }
}

// ============ small GEMM for LoRA u-projections: BK=64, 3-buffer counted ring ============
// EPI2: acc*2*bw[row][col>>4] -> bf16 out at col offset
template<int BM, int BN, int WM, int WN, int K>
__global__ __launch_bounds__(256) void gemmu_kernel(
    const unsigned short* __restrict__ A, int lda,
    const unsigned short* __restrict__ B, int ldb,
    const float* __restrict__ bw,
    unsigned short* __restrict__ outp, int ldo, int ocol) {
  constexpr int WRM = WM / 16, WRN = WN / 16;
  constexpr int NWN = BN / WN;
  constexpr int NT  = K / 64;
  constexpr int NBUF = 3;
  constexpr int AISS = BM * 64 * 2 / 4096;   // gload_lds/thread for A per tile (=2)
  constexpr int BISS = BN * 64 * 2 / 4096;
  constexpr int LOADS = AISS + BISS;
  static_assert((BM / WM) * (BN / WN) == 4 && NT >= NBUF, "geometry");
  __shared__ __align__(16) unsigned short lA[NBUF * BM * 64];
  __shared__ __align__(16) unsigned short lB[NBUF * BN * 64];

  const int tid  = threadIdx.x;
  const int wid  = tid >> 6, lane = tid & 63;
  const int wr   = wid / NWN, wc = wid % NWN;
  const int bm   = blockIdx.x * BM, bn = blockIdx.y * BN;
  const int l15  = lane & 15;
  const int kc0  = ((lane >> 4) ^ (lane & 7)) * 8;
  const int kc1  = (((lane >> 4) + 4) ^ (lane & 7)) * 8;

  f32x4 acc[WRM][WRN] = {};

  auto stage = [&](int buf, int t) {
    #pragma unroll
    for (int i = 0; i < AISS; i++) {
      int row = (wid * AISS + i) * 8 + (lane >> 3);
      __builtin_amdgcn_global_load_lds(
          (const AS1 void*)(A + (size_t)(bm + row) * lda + (size_t)t * 64
                              + (((lane & 7) ^ (row & 7)) * 8)),
          (AS3 void*)(lA + buf * (BM * 64) + (wid * AISS + i) * 512), 16, 0, 0);
    }
    #pragma unroll
    for (int i = 0; i < BISS; i++) {
      int row = (wid * BISS + i) * 8 + (lane >> 3);
      __builtin_amdgcn_global_load_lds(
          (const AS1 void*)(B + (size_t)(bn + row) * ldb + (size_t)t * 64
                              + (((lane & 7) ^ (row & 7)) * 8)),
          (AS3 void*)(lB + buf * (BN * 64) + (wid * BISS + i) * 512), 16, 0, 0);
    }
  };
  auto compute = [&](int buf) {
    const unsigned short* pA = lA + buf * (BM * 64);
    const unsigned short* pB = lB + buf * (BN * 64);
    bf16x8 af[WRM][2], bfv[WRN][2];
    #pragma unroll
    for (int m = 0; m < WRM; m++) {
      int ro = (wr * WM + m * 16 + l15) * 64;
      af[m][0] = *(const bf16x8*)(pA + ro + kc0);
      af[m][1] = *(const bf16x8*)(pA + ro + kc1);
    }
    #pragma unroll
    for (int n = 0; n < WRN; n++) {
      int ro = (wc * WN + n * 16 + l15) * 64;
      bfv[n][0] = *(const bf16x8*)(pB + ro + kc0);
      bfv[n][1] = *(const bf16x8*)(pB + ro + kc1);
    }
    #pragma unroll
    for (int m = 0; m < WRM; m++)
      #pragma unroll
      for (int n = 0; n < WRN; n++) {
        acc[m][n] = __builtin_amdgcn_mfma_f32_16x16x32_bf16(af[m][0], bfv[n][0], acc[m][n], 0, 0, 0);
        acc[m][n] = __builtin_amdgcn_mfma_f32_16x16x32_bf16(af[m][1], bfv[n][1], acc[m][n], 0, 0, 0);
      }
  };

  stage(0, 0); stage(1, 1); stage(2, 2);
  wvm<2 * LOADS>();
  __builtin_amdgcn_s_barrier();

  int bt = 0;
  for (int t = 0; t < NT; ++t) {
    compute(bt);
    __builtin_amdgcn_s_barrier();
    if (t + 1 < NT) {
      if (t + NBUF < NT) stage(bt, t + NBUF);
      int newer = (t + NBUF < NT) ? (NBUF - 1) : (NT - 2 - t);
      if (newer >= 2)      wvm<2 * LOADS>();
      else if (newer == 1) wvm<LOADS>();
      else                 wvm<0>();
      __builtin_amdgcn_s_barrier();
      bt = (bt == NBUF - 1) ? 0 : bt + 1;
    }
  }

  const int r0 = bm + wr * WM;
  const int c0 = bn + wc * WN;
  #pragma unroll
  for (int m = 0; m < WRM; m++)
    #pragma unroll
    for (int n = 0; n < WRN; n++) {
      int col  = c0 + n * 16 + l15;
      int rowb = r0 + m * 16 + ((lane >> 4) << 2);
      #pragma unroll
      for (int r = 0; r < 4; r++) {
        float v = acc[m][n][r] * 2.0f * bw[(rowb + r) * 4 + (col >> 4)];
        outp[(size_t)(rowb + r) * ldo + ocol + col] = f2bf(v);
      }
    }
}

extern "C" void kernel_launch(void* const* d_in, const int* in_sizes, int n_in,
                              void* d_out, int out_size, void* d_ws, size_t ws_size,
                              hipStream_t stream) {
  const float* x  = (const float*)d_in[0];
  const float* bw = (const float*)d_in[1];
  const float* W1 = (const float*)d_in[2];
  const float* b1 = (const float*)d_in[3];
  const float* W2 = (const float*)d_in[4];
  const float* b2 = (const float*)d_in[5];
  const float* A1 = (const float*)d_in[6];
  const float* B1 = (const float*)d_in[7];
  const float* A2 = (const float*)d_in[8];
  const float* B2 = (const float*)d_in[9];
  float* out = (float*)d_out;

  char* w = (char*)d_ws;
  unsigned short* xaug = (unsigned short*)w;  w += (size_t)NR * K1 * 2;       // 18.9 MB
  unsigned short* haug = (unsigned short*)w;  w += (size_t)NR * K2 * 2;       // 69.2 MB
  unsigned short* W1cT = (unsigned short*)w;  w += (size_t)DHID * K1 * 2;     // 2.36 MB
  unsigned short* W2cT = (unsigned short*)w;  w += (size_t)DOUT * K2 * 2;     // 2.16 MB
  unsigned short* A1T  = (unsigned short*)w;  w += (size_t)64 * DIN * 2;
  unsigned short* A2T  = (unsigned short*)w;  w += (size_t)64 * DHID * 2;

  // --- preprocessing ---
  cvt_x_kernel<<<NR * DIN / 4 / 256, 256, 0, stream>>>(x, xaug);
  tconv_kernel<512, 2048, K1, 0><<<dim3(64, 16), 256, 0, stream>>>(W1, W1cT);
  tconv_kernel<64, 2048, K1, 512><<<dim3(64, 2), 256, 0, stream>>>(B1, W1cT);
  tconv_kernel<2048, 512, K2, 0><<<dim3(16, 64), 256, 0, stream>>>(W2, W2cT);
  tconv_kernel<64, 512, K2, 2048><<<dim3(16, 2), 256, 0, stream>>>(B2, W2cT);
  rearrA_kernel<<<128, 256, 0, stream>>>(A1, A1T, 512);
  rearrA_kernel<<<512, 256, 0, stream>>>(A2, A2T, 2048);

  // --- u1 = 2*bw ⊙ (x @ A1cat)  -> xaug[:, 512:576]  (BK=64 ring) ---
  gemmu_kernel<64, 64, 32, 32, 512><<<dim3(NR / 64, 1), 256, 0, stream>>>(
      xaug, K1, A1T, DIN, bw, xaug, K1, 512);
  // --- h = gelu(xaug @ [W1;B1cat] + b1) -> haug[:, 0:2048]  (256x256, 8 waves) ---
  gemmx_kernel<256, 256, 8, K1, 0><<<dim3(NR / 256, DHID / 256), 512, 0, stream>>>(
      xaug, K1, W1cT, K1, b1, haug, K2, 0);
  // --- u2 = 2*bw ⊙ (h @ A2cat) -> haug[:, 2048:2112]  (BK=64 ring) ---
  gemmu_kernel<64, 64, 32, 32, 2048><<<dim3(NR / 64, 1), 256, 0, stream>>>(
      haug, K2, A2T, DHID, bw, haug, K2, 2048);
  // --- out = haug @ [W2;B2cat] + b2 (fp32)  (128x128, 4 waves, 2 blocks/CU) ---
  gemmx_kernel<128, 128, 4, K2, 1><<<dim3(NR / 128, DOUT / 128), 256, 0, stream>>>(
      haug, K2, W2cT, K2, b2, out, DOUT, 0);
}